// Round 1
// baseline (59.424 us; speedup 1.0000x reference)
//
#include <hip/hip_runtime.h>
#include <hip/hip_bf16.h>

typedef __attribute__((ext_vector_type(8))) short short8;
typedef __attribute__((ext_vector_type(4))) float f32x4;

#define DEG 5
#define FDIM 128
#define MT 64
#define NTHR 256
#define LROW 136   // 128 + 8 shorts pad -> conflict-balanced b128 reads

__device__ __forceinline__ short f2bf(float f) {
    // round-to-nearest-even f32 -> bf16 (finite data; no NaN handling needed)
    unsigned u = __builtin_bit_cast(unsigned, f);
    unsigned r = (u + 0x7fffu + ((u >> 16) & 1u)) >> 16;
    return (short)(r & 0xffffu);
}

__global__ __launch_bounds__(NTHR) void shapley_gnn_kernel(
    const float* __restrict__ x,
    const int* __restrict__ col,
    const float* __restrict__ W,
    float* __restrict__ out,
    int n)
{
    __shared__ short sS[MT * LROW];     // 17408 B  (shapley rows, bf16 bits)
    __shared__ short sW[FDIM * LROW];   // 34816 B  (W rows, bf16 bits)
    __shared__ int sIdx[MT * DEG];      // 1280 B

    const int tid = threadIdx.x;
    const int base = blockIdx.x * MT;

    // ---- stage neighbor indices (contiguous load) ----
    for (int i = tid; i < MT * DEG; i += NTHR) {
        int e = base * DEG + i;
        sIdx[i] = (e < n * DEG) ? col[e] : 0;
    }

    // ---- stage W -> bf16 in LDS: 128 rows x 16 chunks of 8 floats ----
    for (int t = tid; t < FDIM * 16; t += NTHR) {
        int r = t >> 4;
        int c = t & 15;
        const float4* wp = reinterpret_cast<const float4*>(W + r * FDIM + c * 8);
        float4 w0 = wp[0];
        float4 w1 = wp[1];
        short8 v;
        v[0] = f2bf(w0.x); v[1] = f2bf(w0.y); v[2] = f2bf(w0.z); v[3] = f2bf(w0.w);
        v[4] = f2bf(w1.x); v[5] = f2bf(w1.y); v[6] = f2bf(w1.z); v[7] = f2bf(w1.w);
        *reinterpret_cast<short8*>(&sW[r * LROW + c * 8]) = v;
    }
    __syncthreads();

    // ---- phase 1: gather neighbors + exact-Shapley linear combine -> bf16 LDS ----
    // Exact collapse of the subset enumeration (slots are symmetric, c1 depends
    // only on |S|):  s_i = (1 + 147/360) * x_i + (-29/600) * sum_j x_nbr[j]
    const float CSELF = 1.4083333333333334f;   // 1 + 147/360
    const float ALPHA = -0.04833333333333333f; // -29/600

    for (int t = tid; t < MT * 16; t += NTHR) {
        int m = t >> 4;
        int c = t & 15;
        int node = base + m;
        float a0, a1, a2, a3, a4, a5, a6, a7;
        if (node < n) {
            const float4* xp = reinterpret_cast<const float4*>(x + (size_t)node * FDIM + c * 8);
            float4 s0 = xp[0], s1 = xp[1];
            a0 = CSELF * s0.x; a1 = CSELF * s0.y; a2 = CSELF * s0.z; a3 = CSELF * s0.w;
            a4 = CSELF * s1.x; a5 = CSELF * s1.y; a6 = CSELF * s1.z; a7 = CSELF * s1.w;
            #pragma unroll
            for (int j = 0; j < DEG; ++j) {
                int nb = sIdx[m * DEG + j];
                const float4* np = reinterpret_cast<const float4*>(x + (size_t)nb * FDIM + c * 8);
                float4 b0 = np[0], b1 = np[1];
                a0 += ALPHA * b0.x; a1 += ALPHA * b0.y; a2 += ALPHA * b0.z; a3 += ALPHA * b0.w;
                a4 += ALPHA * b1.x; a5 += ALPHA * b1.y; a6 += ALPHA * b1.z; a7 += ALPHA * b1.w;
            }
        } else {
            a0 = a1 = a2 = a3 = a4 = a5 = a6 = a7 = 0.f;
        }
        short8 v;
        v[0] = f2bf(a0); v[1] = f2bf(a1); v[2] = f2bf(a2); v[3] = f2bf(a3);
        v[4] = f2bf(a4); v[5] = f2bf(a5); v[6] = f2bf(a6); v[7] = f2bf(a7);
        *reinterpret_cast<short8*>(&sS[m * LROW + c * 8]) = v;
    }
    __syncthreads();

    // ---- phase 2: out = relu(S @ W^T) via mfma_f32_16x16x32_bf16 ----
    // A fragment: lane l holds S[tile_row = l&15][k = kk*32 + (l>>4)*8 .. +8]
    // B fragment: lane l holds W[outcol  = l&15][k = ...] (row-contiguous, m92 pattern)
    // D mapping (m89-verified): D[(l>>4)*4 + i][l&15]
    const int wave = tid >> 6;
    const int lane = tid & 63;
    const int lr = lane & 15;
    const int lg = lane >> 4;

    short8 afrag[4];
    const short* arow = &sS[(wave * 16 + lr) * LROW];
    #pragma unroll
    for (int kk = 0; kk < 4; ++kk)
        afrag[kk] = *reinterpret_cast<const short8*>(arow + kk * 32 + lg * 8);

    f32x4 acc[8];
    #pragma unroll
    for (int t = 0; t < 8; ++t) acc[t] = (f32x4){0.f, 0.f, 0.f, 0.f};

    #pragma unroll
    for (int t = 0; t < 8; ++t) {
        const short* brow = &sW[(t * 16 + lr) * LROW];
        #pragma unroll
        for (int kk = 0; kk < 4; ++kk) {
            short8 bfrag = *reinterpret_cast<const short8*>(brow + kk * 32 + lg * 8);
            acc[t] = __builtin_amdgcn_mfma_f32_16x16x32_bf16(afrag[kk], bfrag, acc[t], 0, 0, 0);
        }
    }

    // ---- epilogue: relu + store ----
    #pragma unroll
    for (int t = 0; t < 8; ++t) {
        #pragma unroll
        for (int i = 0; i < 4; ++i) {
            int nrow = base + wave * 16 + lg * 4 + i;
            if (nrow < n) {
                float v = acc[t][i];
                out[(size_t)nrow * FDIM + t * 16 + lr] = v > 0.f ? v : 0.f;
            }
        }
    }
}

extern "C" void kernel_launch(void* const* d_in, const int* in_sizes, int n_in,
                              void* d_out, int out_size, void* d_ws, size_t ws_size,
                              hipStream_t stream) {
    const float* x  = (const float*)d_in[0];
    const int* ei   = (const int*)d_in[1];
    const float* W  = (const float*)d_in[2];
    float* out      = (float*)d_out;

    int n = in_sizes[0] / FDIM;                   // 100000 nodes
    const int* col = ei + (size_t)n * DEG;        // second row of edge_index

    int blocks = (n + MT - 1) / MT;
    hipLaunchKernelGGL(shapley_gnn_kernel, dim3(blocks), dim3(NTHR), 0, stream,
                       x, col, W, out, n);
}